// Round 17
// baseline (99.467 us; speedup 1.0000x reference)
//
#include <hip/hip_runtime.h>
#include <math.h>

#define LSEQ 1024
#define DDIM 256
#define NC 128         // chunks along L (scan pipeline)
#define CHUNK 8
#define NSC 256        // stats chunks (4 rows each)
#define CSTR 144
#define PI_F 3.14159265358979323846f

// coef row layout (per b,l), 36 planes = 16 bank + 4 joint + 16 pos:
// [0:36) Kre  [36:72) Kim  [72:108) Qre  [108:144) Qim
// (Q weights folded: bank 0.025, joint 0.1, pos 0.5. Gate via jps->gate[].)
// SS stats layout: SS[b][d][chunk]{sum,sq} -> per-thread contiguous prefix reads.

// ---------------- A: phases+stats+jps (bid<512) | V matmul (bid>=512) ----------------
__global__ void kA(const float* __restrict__ x, const float* __restrict__ kp,
                   const float* __restrict__ qp, const float* __restrict__ vp,
                   const float* __restrict__ pf, float* __restrict__ coef,
                   float* __restrict__ V, float* __restrict__ SS,
                   float* __restrict__ jps) {
    int bid = blockIdx.x, t = threadIdx.x;
    __shared__ __align__(16) float xs[4][DDIM];
    __shared__ float part[4][32][2];
    __shared__ float phi[4][32];
    __shared__ float jv[4][8];      // per-row joint KEY (re 0-3, im 4-7)
    if (bid < 512) {
        int r0 = bid * 4;
        {
            const float4* src = (const float4*)(x + (size_t)r0 * DDIM);
            ((float4*)&xs[0][0])[t] = src[t];
        }
        __syncthreads();
        {   // stats: this block's 4 rows are stats chunk (b = bid>>8, c = bid&255)
            float v0 = xs[0][t], v1 = xs[1][t], v2 = xs[2][t], v3 = xs[3][t];
            float2 st;
            st.x = v0 + v1 + v2 + v3;
            st.y = v0*v0 + v1*v1 + v2*v2 + v3*v3;
            *(float2*)&SS[((size_t)((bid >> 8) * 256 + t) * NSC + (bid & 255)) * 2] = st;
        }
        {   // 4 rows x 32 dots x 2 splits
            int r = t >> 6, rem = t & 63, j5 = rem >> 1, s = rem & 1;
            const float* W = (j5 < 16) ? kp : qp;
            int j = j5 & 15, i0 = s * 128;
            const float* xr = &xs[r][0];
            float acc = 0.f;
            #pragma unroll 8
            for (int i = 0; i < 128; ++i) acc += xr[i0 + i] * W[(i0 + i) * 16 + j];
            part[r][j5][s] = acc;
        }
        __syncthreads();
        if (t < 128) {
            int r = t >> 5, j5 = t & 31;
            float ph = tanhf(part[r][j5][0] + part[r][j5][1]) * PI_F;
            phi[r][j5] = ph;
            float s, c; sincosf(ph, &s, &c);   // SIN FIRST
            int j = j5 & 15;
            float* crow = coef + (size_t)(r0 + r) * CSTR;
            if (j5 < 16) { crow[j] = c;               crow[36 + j] = s; }
            else         { crow[72 + j] = 0.025f * c; crow[108 + j] = 0.025f * s; }
        }
        __syncthreads();
        if (t < 32) {
            int r = t >> 3, k = t & 7, p = k & 3;
            const float* p4 = &phi[r][0] + ((k < 4) ? 0 : 16);
            float sum = p4[p] + p4[4 + p] + p4[8 + p] + p4[12 + p];
            float s, c; sincosf(sum, &s, &c);
            float* crow = coef + (size_t)(r0 + r) * CSTR;
            if (k < 4) { crow[16 + p] = c;        crow[52 + p] = s;
                         jv[r][p] = c;            jv[r][4 + p] = s; }
            else       { crow[88 + p] = 0.1f * c; crow[124 + p] = 0.1f * s; }
        }
        if (t >= 64 && t < 128) {
            int u = t - 64, r = u >> 4, pl = u & 15;
            int l = (r0 + r) & (LSEQ - 1);
            float a = (((float)l * pf[pl]) * 2.0f) * PI_F;
            float s, c; sincosf(a, &s, &c);
            float* crow = coef + (size_t)(r0 + r) * CSTR;
            crow[20 + pl] = c;        crow[56 + pl] = s;
            crow[92 + pl] = 0.5f * c; crow[128 + pl] = 0.5f * s;
        }
        __syncthreads();
        if (t < 8)   // joint-key 4-row partial sums for the gate prefix
            jps[(size_t)bid * 8 + t] = jv[0][t] + jv[1][t] + jv[2][t] + jv[3][t];
    } else {   // V = x @ value_proj (4 rows per thread-column)
        int r0 = (bid - 512) * 4;
        {
            const float4* src = (const float4*)(x + (size_t)r0 * DDIM);
            ((float4*)&xs[0][0])[t] = src[t];
        }
        __syncthreads();
        float a0 = 0.f, a1 = 0.f, a2 = 0.f, a3 = 0.f;
        const float4* x40 = (const float4*)&xs[0][0];
        const float4* x41 = (const float4*)&xs[1][0];
        const float4* x42 = (const float4*)&xs[2][0];
        const float4* x43 = (const float4*)&xs[3][0];
        #pragma unroll 4
        for (int i4 = 0; i4 < 64; ++i4) {
            float w0 = vp[(4*i4+0) * DDIM + t];
            float w1 = vp[(4*i4+1) * DDIM + t];
            float w2 = vp[(4*i4+2) * DDIM + t];
            float w3 = vp[(4*i4+3) * DDIM + t];
            float4 v;
            v = x40[i4]; a0 += v.x*w0 + v.y*w1 + v.z*w2 + v.w*w3;
            v = x41[i4]; a1 += v.x*w0 + v.y*w1 + v.z*w2 + v.w*w3;
            v = x42[i4]; a2 += v.x*w0 + v.y*w1 + v.z*w2 + v.w*w3;
            v = x43[i4]; a3 += v.x*w0 + v.y*w1 + v.z*w2 + v.w*w3;
        }
        V[(size_t)(r0+0)*DDIM + t] = a0;
        V[(size_t)(r0+1)*DDIM + t] = a1;
        V[(size_t)(r0+2)*DDIM + t] = a2;
        V[(size_t)(r0+3)*DDIM + t] = a3;
    }
}

// ---------------- C: LTM+stats (bid<512) | chunksum halves + gate (512 blocks) ----------------
__global__ void kC(const float* __restrict__ x, const float* __restrict__ SS,
                   const float* __restrict__ lkp,
                   const float* __restrict__ bre, const float* __restrict__ bim,
                   float* __restrict__ pers, const float* __restrict__ coef,
                   const float* __restrict__ V, const float* __restrict__ jps,
                   float* __restrict__ gate, float* __restrict__ S) {
    int bid = blockIdx.x, t = threadIdx.x;
    __shared__ float ins[4][768];
    __shared__ float part[4][16][4];
    __shared__ float csn[4][2][16];
    __shared__ float jrow[CHUNK][8];
    __shared__ float segp[8][9];
    __shared__ float basech[8];
    __shared__ float mag[CHUNK][4];
    __shared__ float gl[CHUNK];
    if (bid < 512) {
        int b = bid >> 8, c = bid & 255;
        int r0 = bid * 4;
        {
            #pragma unroll
            for (int r = 0; r < 4; ++r)
                ins[r][t] = x[(size_t)(r0 + r) * DDIM + t];
        }
        {   // running stats: contiguous per-thread SS prefix (float4, 8 chains)
            const float2* pp = (const float2*)(SS + (size_t)(b * 256 + t) * NSC * 2);
            const float4* p4 = (const float4*)pp;
            float s0=0.f,s1=0.f,s2=0.f,s3=0.f,q0=0.f,q1=0.f,q2=0.f,q3=0.f;
            int n4 = c >> 1, i = 0;
            for (; i + 4 <= n4; i += 4) {
                float4 a = p4[i], bb = p4[i+1], cc = p4[i+2], dd = p4[i+3];
                s0 += a.x + a.z;   q0 += a.y + a.w;
                s1 += bb.x + bb.z; q1 += bb.y + bb.w;
                s2 += cc.x + cc.z; q2 += cc.y + cc.w;
                s3 += dd.x + dd.z; q3 += dd.y + dd.w;
            }
            for (; i < n4; ++i) { float4 a = p4[i]; s0 += a.x + a.z; q0 += a.y + a.w; }
            if (c & 1) { float2 e = pp[c - 1]; s0 += e.x; q0 += e.y; }
            float cs  = (s0 + s1) + (s2 + s3);
            float css = (q0 + q1) + (q2 + q3);
            #pragma unroll
            for (int r = 0; r < 4; ++r) {
                float v = ins[r][t];
                cs += v; css += v * v;
                int l = c * 4 + r;
                float inv = 1.0f / (float)(l + 1);
                float m = cs * inv;
                float var = css * inv - m * m;
                ins[r][256 + t] = m;
                ins[r][512 + t] = sqrtf(fmaxf(var, 1e-8f));
            }
        }
        __syncthreads();
        {   // 4 rows x 16 outs x 4 splits of 192
            int r = t >> 6, rem = t & 63, j = rem >> 2, h = rem & 3;
            int i0 = h * 192;
            const float* ir = &ins[r][0];
            float acc = 0.f;
            #pragma unroll 8
            for (int i = 0; i < 192; ++i) acc += ir[i0 + i] * lkp[(i0 + i) * 16 + j];
            part[r][j][h] = acc;
        }
        __syncthreads();
        if (t < 64) {
            int r = t >> 4, j = t & 15;
            const float* pp = &part[r][j][0];
            float th = tanhf(pp[0] + pp[1] + pp[2] + pp[3]) * PI_F;
            float s, c; sincosf(th, &s, &c);   // SIN FIRST
            csn[r][0][j] = c; csn[r][1][j] = s;
        }
        __syncthreads();
        float a0 = 0.f, a1 = 0.f, a2 = 0.f, a3 = 0.f;
        #pragma unroll
        for (int pl = 0; pl < 16; ++pl) {
            float br = bre[pl * DDIM + t], bi = bim[pl * DDIM + t];
            a0 += br * csn[0][0][pl] + bi * csn[0][1][pl];
            a1 += br * csn[1][0][pl] + bi * csn[1][1][pl];
            a2 += br * csn[2][0][pl] + bi * csn[2][1][pl];
            a3 += br * csn[3][0][pl] + bi * csn[3][1][pl];
        }
        pers[(size_t)(r0+0)*DDIM + t] = a0;
        pers[(size_t)(r0+1)*DDIM + t] = a1;
        pers[(size_t)(r0+2)*DDIM + t] = a2;
        pers[(size_t)(r0+3)*DDIM + t] = a3;
    } else {   // chunksum halves: 512 blocks (b, c<128, half), CHUNK=8
        int bid2 = bid - 512;
        int b = bid2 >> 8, rem = bid2 & 255, c = rem >> 1, half = rem & 1;
        int row0 = b * LSEQ + c * CHUNK;
        const float* cr0 = coef + (size_t)row0 * CSTR;
        float vbuf[CHUNK];
        #pragma unroll
        for (int l = 0; l < CHUNK; ++l)
            vbuf[l] = V[((size_t)(row0 + l)) * DDIM + t];
        size_t base = ((size_t)(b * NC + c) * 72) * DDIM + t;
        if (half == 0) {
            // gate: per-row joint keys + segmented jps prefix (jps chunks before = 2c)
            if (t < CHUNK * 8) {
                int l = t >> 3, ch = t & 7;
                int off = (ch < 4) ? (16 + ch) : (48 + ch);
                jrow[l][ch] = coef[(size_t)(row0 + l) * CSTR + off];
            }
            if (t >= 128 && t < 192) {   // 64 threads: 8 segs x 8 ch, 4-chain unroll
                int u = t - 128, ch = u & 7, seg = u >> 3;
                int lo = seg * 32, hi = min(2 * c, lo + 32);
                const float* jp = jps + (size_t)b * 256 * 8 + ch;
                float sa = 0.f, sb = 0.f, sc2 = 0.f, sd = 0.f;
                int sc = lo;
                for (; sc + 4 <= hi; sc += 4) {
                    sa  += jp[(size_t)(sc+0) * 8];
                    sb  += jp[(size_t)(sc+1) * 8];
                    sc2 += jp[(size_t)(sc+2) * 8];
                    sd  += jp[(size_t)(sc+3) * 8];
                }
                for (; sc < hi; ++sc) sa += jp[(size_t)sc * 8];
                segp[seg][ch] = (sa + sb) + (sc2 + sd);
            }
            __syncthreads();
            if (t < 8) {
                float s = 0.f;
                #pragma unroll
                for (int g = 0; g < 8; ++g) s += segp[g][t];
                basech[t] = s;
            }
            __syncthreads();
            if (t < 4) {
                float re = basech[t], im = basech[4 + t];
                #pragma unroll
                for (int l = 0; l < CHUNK; ++l) {
                    mag[l][t] = sqrtf(re * re + im * im);  // exclusive
                    re += jrow[l][t]; im += jrow[l][4 + t];
                }
            }
            __syncthreads();
            if (t < CHUNK) {
                float m = 0.25f * (mag[t][0] + mag[t][1] + mag[t][2] + mag[t][3]);
                float nr = m / sqrtf(fmaxf((float)(c * CHUNK + t), 1.0f));
                float sup = 0.5f * (1.0f - tanhf(5.0f * (nr - 0.3f)));
                float gg = 1.0f / (1.0f + expf(-5.0f * (sup - 0.5f)));
                gl[t] = gg;
                gate[b * LSEQ + c * CHUNK + t] = gg;
            }
            __syncthreads();
            float sre[20], sim[20];
            #pragma unroll
            for (int i = 0; i < 20; ++i) { sre[i] = 0.f; sim[i] = 0.f; }
            #pragma unroll
            for (int l = 0; l < CHUNK; ++l) {
                const float* cr = cr0 + l * CSTR;   // block-uniform -> s_load
                float vg = vbuf[l] * gl[l];
                #pragma unroll
                for (int q = 0; q < 5; ++q) {
                    #pragma unroll
                    for (int j = 0; j < 4; ++j) {
                        sre[4*q+j] += cr[4*q+j] * vg;
                        sim[4*q+j] += cr[36 + 4*q+j] * vg;
                    }
                }
            }
            #pragma unroll
            for (int i = 0; i < 20; ++i) {
                S[base + (size_t)i * DDIM] = sre[i];
                S[base + (size_t)(36 + i) * DDIM] = sim[i];
            }
        } else {   // ungated planes q5-8
            float sre[16], sim[16];
            #pragma unroll
            for (int i = 0; i < 16; ++i) { sre[i] = 0.f; sim[i] = 0.f; }
            #pragma unroll
            for (int l = 0; l < CHUNK; ++l) {
                const float* cr = cr0 + l * CSTR;
                float v = vbuf[l];
                #pragma unroll
                for (int q = 5; q < 9; ++q) {
                    int a = 4*q - 20;
                    #pragma unroll
                    for (int j = 0; j < 4; ++j) {
                        sre[a+j] += cr[4*q+j] * v;
                        sim[a+j] += cr[36 + 4*q+j] * v;
                    }
                }
            }
            #pragma unroll
            for (int i = 0; i < 16; ++i) {
                S[base + (size_t)(20 + i) * DDIM] = sre[i];
                S[base + (size_t)(56 + i) * DDIM] = sim[i];
            }
        }
    }
}

// ---------------- D: exclusive prefix over chunks (72 x 4 x 2 blocks, 64 thr) ----------------
__global__ void kD(float* __restrict__ S) {
    int q = blockIdx.x, b = blockIdx.z;
    int d = blockIdx.y * 64 + threadIdx.x;
    float acc = 0.f;
    for (int batch = 0; batch < NC / 32; ++batch) {
        float r[32];
        #pragma unroll
        for (int i = 0; i < 32; ++i)
            r[i] = S[((size_t)(b * NC + batch * 32 + i) * 72 + q) * DDIM + d];
        #pragma unroll
        for (int i = 0; i < 32; ++i) { float tmp = r[i]; r[i] = acc; acc += tmp; }
        #pragma unroll
        for (int i = 0; i < 32; ++i)
            S[((size_t)(b * NC + batch * 32 + i) * 72 + q) * DDIM + d] = r[i];
    }
}

// ---------------- EF: scan + retrieval + epilogue, plane-split 512 threads (256 blocks) ----------------
__global__ __launch_bounds__(512)
void kEF(const float* __restrict__ x, const float* __restrict__ coef,
         const float* __restrict__ V, const float* __restrict__ gate,
         const float* __restrict__ S, const float* __restrict__ pers,
         const float* __restrict__ op, float* __restrict__ out) {
    int bid = blockIdx.x, t = threadIdx.x;
    int g = t >> 8, tt = t & 255;        // g=0: planes q0-4 (gated); g=1: q5-8 (ungated)
    int b = bid >> 7, c = bid & 127;
    int row0 = b * LSEQ + c * CHUNK;
    __shared__ float gl[CHUNK];
    __shared__ __align__(16) float ts[CHUNK][DDIM];
    __shared__ __align__(16) float abuf[CHUNK][DDIM];
    if (t < CHUNK) gl[t] = gate[row0 + t];
    __syncthreads();
    const float* cr0 = coef + (size_t)row0 * CSTR;
    float vbuf[CHUNK], tpb[CHUNK];
    #pragma unroll
    for (int l = 0; l < CHUNK; ++l) {
        size_t idx = ((size_t)(row0 + l)) * DDIM + tt;
        vbuf[l] = V[idx];
        if (g == 0) tpb[l] = pers[idx];
    }
    float rs[CHUNK];
    size_t base = ((size_t)(b * NC + c) * 72) * DDIM + tt;
    if (g == 0) {   // gated planes: q 0..4, state idx 0..19
        float sre[20], sim[20];
        #pragma unroll
        for (int i = 0; i < 20; ++i) {
            sre[i] = S[base + (size_t)i * DDIM];
            sim[i] = S[base + (size_t)(36 + i) * DDIM];
        }
        #pragma unroll
        for (int l = 0; l < CHUNK; ++l) {
            const float* cr = cr0 + l * CSTR;
            float vg = vbuf[l] * gl[l];
            float rx = 0.f, ry = 0.f, rz = 0.f, rw = 0.f;
            #pragma unroll
            for (int q = 0; q < 5; ++q) {
                sre[4*q+0] += cr[4*q+0] * vg; rx += cr[72+4*q+0] * sre[4*q+0];
                sre[4*q+1] += cr[4*q+1] * vg; ry += cr[72+4*q+1] * sre[4*q+1];
                sre[4*q+2] += cr[4*q+2] * vg; rz += cr[72+4*q+2] * sre[4*q+2];
                sre[4*q+3] += cr[4*q+3] * vg; rw += cr[72+4*q+3] * sre[4*q+3];
                sim[4*q+0] += cr[36+4*q+0] * vg; rx += cr[108+4*q+0] * sim[4*q+0];
                sim[4*q+1] += cr[36+4*q+1] * vg; ry += cr[108+4*q+1] * sim[4*q+1];
                sim[4*q+2] += cr[36+4*q+2] * vg; rz += cr[108+4*q+2] * sim[4*q+2];
                sim[4*q+3] += cr[36+4*q+3] * vg; rw += cr[108+4*q+3] * sim[4*q+3];
            }
            rs[l] = (rx + ry) + (rz + rw);
        }
        #pragma unroll
        for (int l = 0; l < CHUNK; ++l) ts[l][tt] = rs[l] + 0.125f * tpb[l];
    } else {        // ungated planes: q 5..8, state idx 20..35 (local 0..15)
        float sre[16], sim[16];
        #pragma unroll
        for (int i = 0; i < 16; ++i) {
            sre[i] = S[base + (size_t)(20 + i) * DDIM];
            sim[i] = S[base + (size_t)(56 + i) * DDIM];
        }
        #pragma unroll
        for (int l = 0; l < CHUNK; ++l) {
            const float* cr = cr0 + l * CSTR;
            float v = vbuf[l];
            float rx = 0.f, ry = 0.f, rz = 0.f, rw = 0.f;
            #pragma unroll
            for (int q = 5; q < 9; ++q) {
                int a = 4*q - 20;
                sre[a+0] += cr[4*q+0] * v; rx += cr[72+4*q+0] * sre[a+0];
                sre[a+1] += cr[4*q+1] * v; ry += cr[72+4*q+1] * sre[a+1];
                sre[a+2] += cr[4*q+2] * v; rz += cr[72+4*q+2] * sre[a+2];
                sre[a+3] += cr[4*q+3] * v; rw += cr[72+4*q+3] * sre[a+3];
                sim[a+0] += cr[36+4*q+0] * v; rx += cr[108+4*q+0] * sim[a+0];
                sim[a+1] += cr[36+4*q+1] * v; ry += cr[108+4*q+1] * sim[a+1];
                sim[a+2] += cr[36+4*q+2] * v; rz += cr[108+4*q+2] * sim[a+2];
                sim[a+3] += cr[36+4*q+3] * v; rw += cr[108+4*q+3] * sim[a+3];
            }
            rs[l] = (rx + ry) + (rz + rw);
        }
    }
    __syncthreads();
    if (g == 1) {
        #pragma unroll
        for (int l = 0; l < CHUNK; ++l) {
            int lrow = c * CHUNK + l;
            float invn = 1.0f / (2.0f * sqrtf((float)(lrow + 1)));
            ts[l][tt] = (ts[l][tt] + rs[l]) * invn;
        }
    }
    __syncthreads();
    // epilogue: out = x + ts @ out_proj; i-range split across groups
    float acc[CHUNK];
    #pragma unroll
    for (int r = 0; r < CHUNK; ++r) acc[r] = 0.f;
    int i4lo = g * 32;
    #pragma unroll 2
    for (int i4 = i4lo; i4 < i4lo + 32; ++i4) {
        float w0 = op[(4*i4+0) * DDIM + tt];
        float w1 = op[(4*i4+1) * DDIM + tt];
        float w2 = op[(4*i4+2) * DDIM + tt];
        float w3 = op[(4*i4+3) * DDIM + tt];
        #pragma unroll
        for (int r = 0; r < CHUNK; ++r) {
            float4 v = ((const float4*)&ts[r][0])[i4];
            acc[r] += v.x*w0 + v.y*w1 + v.z*w2 + v.w*w3;
        }
    }
    if (g == 1) {
        #pragma unroll
        for (int r = 0; r < CHUNK; ++r) abuf[r][tt] = acc[r];
    }
    __syncthreads();
    if (g == 0) {
        #pragma unroll
        for (int r = 0; r < CHUNK; ++r) {
            size_t row = (size_t)(row0 + r) * DDIM;
            out[row + tt] = x[row + tt] + acc[r] + abuf[r][tt];
        }
    }
}

extern "C" void kernel_launch(void* const* d_in, const int* in_sizes, int n_in,
                              void* d_out, int out_size, void* d_ws, size_t ws_size,
                              hipStream_t stream) {
    const float* x   = (const float*)d_in[0];
    const float* kp  = (const float*)d_in[1];
    const float* qp  = (const float*)d_in[2];
    const float* vp  = (const float*)d_in[3];
    const float* op  = (const float*)d_in[4];
    const float* lkp = (const float*)d_in[5];
    const float* pf  = (const float*)d_in[7];
    const float* bre = (const float*)d_in[10];
    const float* bim = (const float*)d_in[11];
    float* out = (float*)d_out;

    const int B = 2;
    float* w = (float*)d_ws;
    size_t off = 0;
    float* coef  = w + off; off += (size_t)B * LSEQ * CSTR;       // 294912
    float* V     = w + off; off += (size_t)B * LSEQ * DDIM;       // 524288
    float* pers  = w + off; off += (size_t)B * LSEQ * DDIM;
    float* jps   = w + off; off += (size_t)B * 256 * 8;           // 4096
    float* gate  = w + off; off += (size_t)B * LSEQ;              // 2048
    float* SS    = w + off; off += (size_t)B * DDIM * NSC * 2;    // 262144
    float* S     = w + off; off += (size_t)B * NC * 72 * DDIM;    // 4718592
    // total ~25 MB

    kA<<<dim3(1024),      dim3(256), 0, stream>>>(x, kp, qp, vp, pf, coef, V, SS, jps);
    kC<<<dim3(512 + 512), dim3(256), 0, stream>>>(x, SS, lkp, bre, bim, pers,
                                                  coef, V, jps, gate, S);
    kD<<<dim3(72, 4, 2),  dim3(64),  0, stream>>>(S);
    kEF<<<dim3(256),      dim3(512), 0, stream>>>(x, coef, V, gate, S, pers, op, out);
}

// Round 18
// 83.243 us; speedup vs baseline: 1.1949x; 1.1949x over previous
//
#include <hip/hip_runtime.h>
#include <math.h>

#define LSEQ 1024
#define DDIM 256
#define NC 128         // chunks along L (scan pipeline)
#define CHUNK 8
#define NSC 256        // stats chunks (4 rows each)
#define CSTR 144
#define PI_F 3.14159265358979323846f

// coef row layout (per b,l), 36 planes = 16 bank + 4 joint + 16 pos:
// [0:36) Kre  [36:72) Kim  [72:108) Qre  [108:144) Qim
// (Q weights folded: bank 0.025, joint 0.1, pos 0.5. Gate via jps->gate[].)
// Ssum/Ssq layout [chunk][d]: inter-lane coalesced (R17 transpose was a regression).

// ---------------- A: phases+stats+jps (bid<512) | V matmul (bid>=512) ----------------
__global__ void kA(const float* __restrict__ x, const float* __restrict__ kp,
                   const float* __restrict__ qp, const float* __restrict__ vp,
                   const float* __restrict__ pf, float* __restrict__ coef,
                   float* __restrict__ V, float* __restrict__ Ssum,
                   float* __restrict__ Ssq, float* __restrict__ jps) {
    int bid = blockIdx.x, t = threadIdx.x;
    __shared__ __align__(16) float xs[4][DDIM];
    __shared__ float part[4][32][2];
    __shared__ float phi[4][32];
    __shared__ float jv[4][8];      // per-row joint KEY (re 0-3, im 4-7)
    if (bid < 512) {
        int r0 = bid * 4;
        {
            const float4* src = (const float4*)(x + (size_t)r0 * DDIM);
            ((float4*)&xs[0][0])[t] = src[t];
        }
        __syncthreads();
        {   // stats: this block's 4 rows are stats chunk bid
            float v0 = xs[0][t], v1 = xs[1][t], v2 = xs[2][t], v3 = xs[3][t];
            Ssum[bid * DDIM + t] = v0 + v1 + v2 + v3;
            Ssq [bid * DDIM + t] = v0*v0 + v1*v1 + v2*v2 + v3*v3;
        }
        {   // 4 rows x 32 dots x 2 splits
            int r = t >> 6, rem = t & 63, j5 = rem >> 1, s = rem & 1;
            const float* W = (j5 < 16) ? kp : qp;
            int j = j5 & 15, i0 = s * 128;
            const float* xr = &xs[r][0];
            float acc = 0.f;
            #pragma unroll 8
            for (int i = 0; i < 128; ++i) acc += xr[i0 + i] * W[(i0 + i) * 16 + j];
            part[r][j5][s] = acc;
        }
        __syncthreads();
        if (t < 128) {
            int r = t >> 5, j5 = t & 31;
            float ph = tanhf(part[r][j5][0] + part[r][j5][1]) * PI_F;
            phi[r][j5] = ph;
            float s, c; sincosf(ph, &s, &c);   // SIN FIRST
            int j = j5 & 15;
            float* crow = coef + (size_t)(r0 + r) * CSTR;
            if (j5 < 16) { crow[j] = c;               crow[36 + j] = s; }
            else         { crow[72 + j] = 0.025f * c; crow[108 + j] = 0.025f * s; }
        }
        __syncthreads();
        if (t < 32) {
            int r = t >> 3, k = t & 7, p = k & 3;
            const float* p4 = &phi[r][0] + ((k < 4) ? 0 : 16);
            float sum = p4[p] + p4[4 + p] + p4[8 + p] + p4[12 + p];
            float s, c; sincosf(sum, &s, &c);
            float* crow = coef + (size_t)(r0 + r) * CSTR;
            if (k < 4) { crow[16 + p] = c;        crow[52 + p] = s;
                         jv[r][p] = c;            jv[r][4 + p] = s; }
            else       { crow[88 + p] = 0.1f * c; crow[124 + p] = 0.1f * s; }
        }
        if (t >= 64 && t < 128) {
            int u = t - 64, r = u >> 4, pl = u & 15;
            int l = (r0 + r) & (LSEQ - 1);
            float a = (((float)l * pf[pl]) * 2.0f) * PI_F;
            float s, c; sincosf(a, &s, &c);
            float* crow = coef + (size_t)(r0 + r) * CSTR;
            crow[20 + pl] = c;        crow[56 + pl] = s;
            crow[92 + pl] = 0.5f * c; crow[128 + pl] = 0.5f * s;
        }
        __syncthreads();
        if (t < 8)   // joint-key 4-row partial sums for the gate prefix
            jps[(size_t)bid * 8 + t] = jv[0][t] + jv[1][t] + jv[2][t] + jv[3][t];
    } else {   // V = x @ value_proj (4 rows per thread-column)
        int r0 = (bid - 512) * 4;
        {
            const float4* src = (const float4*)(x + (size_t)r0 * DDIM);
            ((float4*)&xs[0][0])[t] = src[t];
        }
        __syncthreads();
        float a0 = 0.f, a1 = 0.f, a2 = 0.f, a3 = 0.f;
        const float4* x40 = (const float4*)&xs[0][0];
        const float4* x41 = (const float4*)&xs[1][0];
        const float4* x42 = (const float4*)&xs[2][0];
        const float4* x43 = (const float4*)&xs[3][0];
        #pragma unroll 4
        for (int i4 = 0; i4 < 64; ++i4) {
            float w0 = vp[(4*i4+0) * DDIM + t];
            float w1 = vp[(4*i4+1) * DDIM + t];
            float w2 = vp[(4*i4+2) * DDIM + t];
            float w3 = vp[(4*i4+3) * DDIM + t];
            float4 v;
            v = x40[i4]; a0 += v.x*w0 + v.y*w1 + v.z*w2 + v.w*w3;
            v = x41[i4]; a1 += v.x*w0 + v.y*w1 + v.z*w2 + v.w*w3;
            v = x42[i4]; a2 += v.x*w0 + v.y*w1 + v.z*w2 + v.w*w3;
            v = x43[i4]; a3 += v.x*w0 + v.y*w1 + v.z*w2 + v.w*w3;
        }
        V[(size_t)(r0+0)*DDIM + t] = a0;
        V[(size_t)(r0+1)*DDIM + t] = a1;
        V[(size_t)(r0+2)*DDIM + t] = a2;
        V[(size_t)(r0+3)*DDIM + t] = a3;
    }
}

// ---------------- C: LTM+stats (bid<512) | chunksum halves + gate (512 blocks) ----------------
__global__ void kC(const float* __restrict__ x, const float* __restrict__ Ssum,
                   const float* __restrict__ Ssq, const float* __restrict__ lkp,
                   const float* __restrict__ bre, const float* __restrict__ bim,
                   float* __restrict__ pers, const float* __restrict__ coef,
                   const float* __restrict__ V, const float* __restrict__ jps,
                   float* __restrict__ gate, float* __restrict__ S) {
    int bid = blockIdx.x, t = threadIdx.x;
    __shared__ float ins[4][768];
    __shared__ float part[4][16][4];
    __shared__ float csn[4][2][16];
    __shared__ float jrow[CHUNK][8];
    __shared__ float segp[8][9];
    __shared__ float basech[8];
    __shared__ float mag[CHUNK][4];
    __shared__ float gl[CHUNK];
    if (bid < 512) {
        int b = bid >> 8, c = bid & 255;
        int r0 = bid * 4;
        {
            #pragma unroll
            for (int r = 0; r < 4; ++r)
                ins[r][t] = x[(size_t)(r0 + r) * DDIM + t];
        }
        {   // running stats: 8-way-unrolled chunk prefix + 4-row replay (coalesced)
            float s0=0.f,s1=0.f,s2=0.f,s3=0.f,s4=0.f,s5=0.f,s6=0.f,s7=0.f;
            float q0=0.f,q1=0.f,q2=0.f,q3=0.f,q4=0.f,q5=0.f,q6=0.f,q7=0.f;
            const float* su = Ssum + (size_t)(b * NSC) * DDIM + t;
            const float* sq = Ssq  + (size_t)(b * NSC) * DDIM + t;
            int cc = 0;
            for (; cc + 8 <= c; cc += 8) {
                s0 += su[(size_t)(cc+0)*DDIM]; q0 += sq[(size_t)(cc+0)*DDIM];
                s1 += su[(size_t)(cc+1)*DDIM]; q1 += sq[(size_t)(cc+1)*DDIM];
                s2 += su[(size_t)(cc+2)*DDIM]; q2 += sq[(size_t)(cc+2)*DDIM];
                s3 += su[(size_t)(cc+3)*DDIM]; q3 += sq[(size_t)(cc+3)*DDIM];
                s4 += su[(size_t)(cc+4)*DDIM]; q4 += sq[(size_t)(cc+4)*DDIM];
                s5 += su[(size_t)(cc+5)*DDIM]; q5 += sq[(size_t)(cc+5)*DDIM];
                s6 += su[(size_t)(cc+6)*DDIM]; q6 += sq[(size_t)(cc+6)*DDIM];
                s7 += su[(size_t)(cc+7)*DDIM]; q7 += sq[(size_t)(cc+7)*DDIM];
            }
            for (; cc < c; ++cc) { s0 += su[(size_t)cc*DDIM]; q0 += sq[(size_t)cc*DDIM]; }
            float cs  = ((s0+s1)+(s2+s3)) + ((s4+s5)+(s6+s7));
            float css = ((q0+q1)+(q2+q3)) + ((q4+q5)+(q6+q7));
            #pragma unroll
            for (int r = 0; r < 4; ++r) {
                float v = ins[r][t];
                cs += v; css += v * v;
                int l = c * 4 + r;
                float inv = 1.0f / (float)(l + 1);
                float m = cs * inv;
                float var = css * inv - m * m;
                ins[r][256 + t] = m;
                ins[r][512 + t] = sqrtf(fmaxf(var, 1e-8f));
            }
        }
        __syncthreads();
        {   // 4 rows x 16 outs x 4 splits of 192
            int r = t >> 6, rem = t & 63, j = rem >> 2, h = rem & 3;
            int i0 = h * 192;
            const float* ir = &ins[r][0];
            float acc = 0.f;
            #pragma unroll 8
            for (int i = 0; i < 192; ++i) acc += ir[i0 + i] * lkp[(i0 + i) * 16 + j];
            part[r][j][h] = acc;
        }
        __syncthreads();
        if (t < 64) {
            int r = t >> 4, j = t & 15;
            const float* pp = &part[r][j][0];
            float th = tanhf(pp[0] + pp[1] + pp[2] + pp[3]) * PI_F;
            float s, c; sincosf(th, &s, &c);   // SIN FIRST
            csn[r][0][j] = c; csn[r][1][j] = s;
        }
        __syncthreads();
        float a0 = 0.f, a1 = 0.f, a2 = 0.f, a3 = 0.f;
        #pragma unroll
        for (int pl = 0; pl < 16; ++pl) {
            float br = bre[pl * DDIM + t], bi = bim[pl * DDIM + t];
            a0 += br * csn[0][0][pl] + bi * csn[0][1][pl];
            a1 += br * csn[1][0][pl] + bi * csn[1][1][pl];
            a2 += br * csn[2][0][pl] + bi * csn[2][1][pl];
            a3 += br * csn[3][0][pl] + bi * csn[3][1][pl];
        }
        pers[(size_t)(r0+0)*DDIM + t] = a0;
        pers[(size_t)(r0+1)*DDIM + t] = a1;
        pers[(size_t)(r0+2)*DDIM + t] = a2;
        pers[(size_t)(r0+3)*DDIM + t] = a3;
    } else {   // chunksum halves: 512 blocks (b, c<128, half), CHUNK=8
        int bid2 = bid - 512;
        int b = bid2 >> 8, rem = bid2 & 255, c = rem >> 1, half = rem & 1;
        int row0 = b * LSEQ + c * CHUNK;
        const float* cr0 = coef + (size_t)row0 * CSTR;
        float vbuf[CHUNK];
        #pragma unroll
        for (int l = 0; l < CHUNK; ++l)
            vbuf[l] = V[((size_t)(row0 + l)) * DDIM + t];
        size_t base = ((size_t)(b * NC + c) * 72) * DDIM + t;
        if (half == 0) {
            // gate: per-row joint keys + segmented jps prefix (jps chunks before = 2c)
            if (t < CHUNK * 8) {
                int l = t >> 3, ch = t & 7;
                int off = (ch < 4) ? (16 + ch) : (48 + ch);
                jrow[l][ch] = coef[(size_t)(row0 + l) * CSTR + off];
            }
            if (t >= 128 && t < 192) {   // 64 threads: 8 segs x 8 ch, 4-chain unroll
                int u = t - 128, ch = u & 7, seg = u >> 3;
                int lo = seg * 32, hi = min(2 * c, lo + 32);
                const float* jp = jps + (size_t)b * 256 * 8 + ch;
                float sa = 0.f, sb = 0.f, sc2 = 0.f, sd = 0.f;
                int sc = lo;
                for (; sc + 4 <= hi; sc += 4) {
                    sa  += jp[(size_t)(sc+0) * 8];
                    sb  += jp[(size_t)(sc+1) * 8];
                    sc2 += jp[(size_t)(sc+2) * 8];
                    sd  += jp[(size_t)(sc+3) * 8];
                }
                for (; sc < hi; ++sc) sa += jp[(size_t)sc * 8];
                segp[seg][ch] = (sa + sb) + (sc2 + sd);
            }
            __syncthreads();
            if (t < 8) {
                float s = 0.f;
                #pragma unroll
                for (int g = 0; g < 8; ++g) s += segp[g][t];
                basech[t] = s;
            }
            __syncthreads();
            if (t < 4) {
                float re = basech[t], im = basech[4 + t];
                #pragma unroll
                for (int l = 0; l < CHUNK; ++l) {
                    mag[l][t] = sqrtf(re * re + im * im);  // exclusive
                    re += jrow[l][t]; im += jrow[l][4 + t];
                }
            }
            __syncthreads();
            if (t < CHUNK) {
                float m = 0.25f * (mag[t][0] + mag[t][1] + mag[t][2] + mag[t][3]);
                float nr = m / sqrtf(fmaxf((float)(c * CHUNK + t), 1.0f));
                float sup = 0.5f * (1.0f - tanhf(5.0f * (nr - 0.3f)));
                float gg = 1.0f / (1.0f + expf(-5.0f * (sup - 0.5f)));
                gl[t] = gg;
                gate[b * LSEQ + c * CHUNK + t] = gg;
            }
            __syncthreads();
            float sre[20], sim[20];
            #pragma unroll
            for (int i = 0; i < 20; ++i) { sre[i] = 0.f; sim[i] = 0.f; }
            #pragma unroll
            for (int l = 0; l < CHUNK; ++l) {
                const float* cr = cr0 + l * CSTR;   // block-uniform -> s_load
                float vg = vbuf[l] * gl[l];
                #pragma unroll
                for (int q = 0; q < 5; ++q) {
                    #pragma unroll
                    for (int j = 0; j < 4; ++j) {
                        sre[4*q+j] += cr[4*q+j] * vg;
                        sim[4*q+j] += cr[36 + 4*q+j] * vg;
                    }
                }
            }
            #pragma unroll
            for (int i = 0; i < 20; ++i) {
                S[base + (size_t)i * DDIM] = sre[i];
                S[base + (size_t)(36 + i) * DDIM] = sim[i];
            }
        } else {   // ungated planes q5-8
            float sre[16], sim[16];
            #pragma unroll
            for (int i = 0; i < 16; ++i) { sre[i] = 0.f; sim[i] = 0.f; }
            #pragma unroll
            for (int l = 0; l < CHUNK; ++l) {
                const float* cr = cr0 + l * CSTR;
                float v = vbuf[l];
                #pragma unroll
                for (int q = 5; q < 9; ++q) {
                    int a = 4*q - 20;
                    #pragma unroll
                    for (int j = 0; j < 4; ++j) {
                        sre[a+j] += cr[4*q+j] * v;
                        sim[a+j] += cr[36 + 4*q+j] * v;
                    }
                }
            }
            #pragma unroll
            for (int i = 0; i < 16; ++i) {
                S[base + (size_t)(20 + i) * DDIM] = sre[i];
                S[base + (size_t)(56 + i) * DDIM] = sim[i];
            }
        }
    }
}

// ---------------- D: exclusive prefix over chunks (72 x 4 x 2 blocks, 64 thr) ----------------
__global__ void kD(float* __restrict__ S) {
    int q = blockIdx.x, b = blockIdx.z;
    int d = blockIdx.y * 64 + threadIdx.x;
    float acc = 0.f;
    for (int batch = 0; batch < NC / 32; ++batch) {
        float r[32];
        #pragma unroll
        for (int i = 0; i < 32; ++i)
            r[i] = S[((size_t)(b * NC + batch * 32 + i) * 72 + q) * DDIM + d];
        #pragma unroll
        for (int i = 0; i < 32; ++i) { float tmp = r[i]; r[i] = acc; acc += tmp; }
        #pragma unroll
        for (int i = 0; i < 32; ++i)
            S[((size_t)(b * NC + batch * 32 + i) * 72 + q) * DDIM + d] = r[i];
    }
}

// ---------------- EF: scan + retrieval + epilogue, plane-split 512 threads (256 blocks) ----------------
__global__ __launch_bounds__(512)
void kEF(const float* __restrict__ x, const float* __restrict__ coef,
         const float* __restrict__ V, const float* __restrict__ gate,
         const float* __restrict__ S, const float* __restrict__ pers,
         const float* __restrict__ op, float* __restrict__ out) {
    int bid = blockIdx.x, t = threadIdx.x;
    int g = t >> 8, tt = t & 255;        // g=0: planes q0-4 (gated); g=1: q5-8 (ungated)
    int b = bid >> 7, c = bid & 127;
    int row0 = b * LSEQ + c * CHUNK;
    __shared__ float gl[CHUNK];
    __shared__ __align__(16) float ts[CHUNK][DDIM];
    __shared__ __align__(16) float abuf[CHUNK][DDIM];
    if (t < CHUNK) gl[t] = gate[row0 + t];
    __syncthreads();
    const float* cr0 = coef + (size_t)row0 * CSTR;
    float vbuf[CHUNK], tpb[CHUNK];
    #pragma unroll
    for (int l = 0; l < CHUNK; ++l) {
        size_t idx = ((size_t)(row0 + l)) * DDIM + tt;
        vbuf[l] = V[idx];
        if (g == 0) tpb[l] = pers[idx];
    }
    float rs[CHUNK];
    size_t base = ((size_t)(b * NC + c) * 72) * DDIM + tt;
    if (g == 0) {   // gated planes: q 0..4, state idx 0..19
        float sre[20], sim[20];
        #pragma unroll
        for (int i = 0; i < 20; ++i) {
            sre[i] = S[base + (size_t)i * DDIM];
            sim[i] = S[base + (size_t)(36 + i) * DDIM];
        }
        #pragma unroll
        for (int l = 0; l < CHUNK; ++l) {
            const float* cr = cr0 + l * CSTR;
            float vg = vbuf[l] * gl[l];
            float rx = 0.f, ry = 0.f, rz = 0.f, rw = 0.f;
            #pragma unroll
            for (int q = 0; q < 5; ++q) {
                sre[4*q+0] += cr[4*q+0] * vg; rx += cr[72+4*q+0] * sre[4*q+0];
                sre[4*q+1] += cr[4*q+1] * vg; ry += cr[72+4*q+1] * sre[4*q+1];
                sre[4*q+2] += cr[4*q+2] * vg; rz += cr[72+4*q+2] * sre[4*q+2];
                sre[4*q+3] += cr[4*q+3] * vg; rw += cr[72+4*q+3] * sre[4*q+3];
                sim[4*q+0] += cr[36+4*q+0] * vg; rx += cr[108+4*q+0] * sim[4*q+0];
                sim[4*q+1] += cr[36+4*q+1] * vg; ry += cr[108+4*q+1] * sim[4*q+1];
                sim[4*q+2] += cr[36+4*q+2] * vg; rz += cr[108+4*q+2] * sim[4*q+2];
                sim[4*q+3] += cr[36+4*q+3] * vg; rw += cr[108+4*q+3] * sim[4*q+3];
            }
            rs[l] = (rx + ry) + (rz + rw);
        }
        #pragma unroll
        for (int l = 0; l < CHUNK; ++l) ts[l][tt] = rs[l] + 0.125f * tpb[l];
    } else {        // ungated planes: q 5..8, state idx 20..35 (local 0..15)
        float sre[16], sim[16];
        #pragma unroll
        for (int i = 0; i < 16; ++i) {
            sre[i] = S[base + (size_t)(20 + i) * DDIM];
            sim[i] = S[base + (size_t)(56 + i) * DDIM];
        }
        #pragma unroll
        for (int l = 0; l < CHUNK; ++l) {
            const float* cr = cr0 + l * CSTR;
            float v = vbuf[l];
            float rx = 0.f, ry = 0.f, rz = 0.f, rw = 0.f;
            #pragma unroll
            for (int q = 5; q < 9; ++q) {
                int a = 4*q - 20;
                sre[a+0] += cr[4*q+0] * v; rx += cr[72+4*q+0] * sre[a+0];
                sre[a+1] += cr[4*q+1] * v; ry += cr[72+4*q+1] * sre[a+1];
                sre[a+2] += cr[4*q+2] * v; rz += cr[72+4*q+2] * sre[a+2];
                sre[a+3] += cr[4*q+3] * v; rw += cr[72+4*q+3] * sre[a+3];
                sim[a+0] += cr[36+4*q+0] * v; rx += cr[108+4*q+0] * sim[a+0];
                sim[a+1] += cr[36+4*q+1] * v; ry += cr[108+4*q+1] * sim[a+1];
                sim[a+2] += cr[36+4*q+2] * v; rz += cr[108+4*q+2] * sim[a+2];
                sim[a+3] += cr[36+4*q+3] * v; rw += cr[108+4*q+3] * sim[a+3];
            }
            rs[l] = (rx + ry) + (rz + rw);
        }
    }
    __syncthreads();
    if (g == 1) {
        #pragma unroll
        for (int l = 0; l < CHUNK; ++l) {
            int lrow = c * CHUNK + l;
            float invn = 1.0f / (2.0f * sqrtf((float)(lrow + 1)));
            ts[l][tt] = (ts[l][tt] + rs[l]) * invn;
        }
    }
    __syncthreads();
    // epilogue: out = x + ts @ out_proj; i-range split across groups
    float acc[CHUNK];
    #pragma unroll
    for (int r = 0; r < CHUNK; ++r) acc[r] = 0.f;
    int i4lo = g * 32;
    #pragma unroll 2
    for (int i4 = i4lo; i4 < i4lo + 32; ++i4) {
        float w0 = op[(4*i4+0) * DDIM + tt];
        float w1 = op[(4*i4+1) * DDIM + tt];
        float w2 = op[(4*i4+2) * DDIM + tt];
        float w3 = op[(4*i4+3) * DDIM + tt];
        #pragma unroll
        for (int r = 0; r < CHUNK; ++r) {
            float4 v = ((const float4*)&ts[r][0])[i4];
            acc[r] += v.x*w0 + v.y*w1 + v.z*w2 + v.w*w3;
        }
    }
    if (g == 1) {
        #pragma unroll
        for (int r = 0; r < CHUNK; ++r) abuf[r][tt] = acc[r];
    }
    __syncthreads();
    if (g == 0) {
        #pragma unroll
        for (int r = 0; r < CHUNK; ++r) {
            size_t row = (size_t)(row0 + r) * DDIM;
            out[row + tt] = x[row + tt] + acc[r] + abuf[r][tt];
        }
    }
}

extern "C" void kernel_launch(void* const* d_in, const int* in_sizes, int n_in,
                              void* d_out, int out_size, void* d_ws, size_t ws_size,
                              hipStream_t stream) {
    const float* x   = (const float*)d_in[0];
    const float* kp  = (const float*)d_in[1];
    const float* qp  = (const float*)d_in[2];
    const float* vp  = (const float*)d_in[3];
    const float* op  = (const float*)d_in[4];
    const float* lkp = (const float*)d_in[5];
    const float* pf  = (const float*)d_in[7];
    const float* bre = (const float*)d_in[10];
    const float* bim = (const float*)d_in[11];
    float* out = (float*)d_out;

    const int B = 2;
    float* w = (float*)d_ws;
    size_t off = 0;
    float* coef  = w + off; off += (size_t)B * LSEQ * CSTR;       // 294912
    float* V     = w + off; off += (size_t)B * LSEQ * DDIM;       // 524288
    float* pers  = w + off; off += (size_t)B * LSEQ * DDIM;
    float* jps   = w + off; off += (size_t)B * 256 * 8;           // 4096
    float* gate  = w + off; off += (size_t)B * LSEQ;              // 2048
    float* Ssum  = w + off; off += (size_t)B * NSC * DDIM;        // 131072
    float* Ssq   = w + off; off += (size_t)B * NSC * DDIM;
    float* S     = w + off; off += (size_t)B * NC * 72 * DDIM;    // 4718592
    // total ~25 MB

    kA<<<dim3(1024),      dim3(256), 0, stream>>>(x, kp, qp, vp, pf, coef, V,
                                                  Ssum, Ssq, jps);
    kC<<<dim3(512 + 512), dim3(256), 0, stream>>>(x, Ssum, Ssq, lkp, bre, bim, pers,
                                                  coef, V, jps, gate, S);
    kD<<<dim3(72, 4, 2),  dim3(64),  0, stream>>>(S);
    kEF<<<dim3(256),      dim3(512), 0, stream>>>(x, coef, V, gate, S, pers, op, out);
}